// Round 12
// baseline (153.840 us; speedup 1.0000x reference)
//
#include <hip/hip_runtime.h>
#include <math.h>

#define E_TYPES 20
#define NBLK 2
#define NANG 7
#define CS 384
#define CH 128
#define N_TOK (8 * 2048)
#define TOK 80
#define TPB_MAIN 512
#define KC 128
#define MAX_TILES (N_TOK / TOK + E_TYPES)   // 204 + 20 = 224 (provable upper bound)
#define NPREP 64

// ---- workspace: int control region ----
#define HIST_OFF 0           // 64 x 20 per-block histograms

// ---- workspace: fragment-packed split-bf16 weights (bytes) ----
// 1KB block = 64 lanes x 16B; element (n,k): lane = (n&15)|((k>>3&3)<<4), j=k&7
#define WT1_OFF (256 * 1024)                       // phase-1 concat [768x128] per e
#define WT1_SZ  (20 * 8 * 24 * 2048)               // e x nt(8) x kb(24) x (hi1KB+lo1KB)
#define WTR_OFF (WT1_OFF + WT1_SZ)                 // residual: e x m4(4) x nt(8) x kb(4)
// total end ~13.4 MB

typedef __attribute__((ext_vector_type(8))) short bfrag;
typedef __attribute__((ext_vector_type(4))) float f32x4;
typedef unsigned short (*arr136)[136];

__device__ __forceinline__ void split_bf16(float x, unsigned short& h, unsigned short& l) {
    unsigned int u = __float_as_uint(x);
    unsigned int hb = (u + 0x7FFFu + ((u >> 16) & 1u)) & 0xFFFF0000u;
    h = (unsigned short)(hb >> 16);
    float r = x - __uint_as_float(hb);
    unsigned int v = __float_as_uint(r);
    l = (unsigned short)((v + 0x7FFFu + ((v >> 16) & 1u)) >> 16);
}

// prep1: blocks [0,1600) convert weights to fragment-packed split-bf16;
// blocks [1600,1664) build the per-block token histogram.
__global__ void prep1(const float* __restrict__ Win, const float* __restrict__ Winit,
                      const float* __restrict__ Wb1, const float* __restrict__ Wb2,
                      const int* __restrict__ aatype, int* __restrict__ wsI,
                      unsigned short* __restrict__ wt) {
    __shared__ int lh[E_TYPES];
    int bid = blockIdx.x;
    int t = threadIdx.x;
    if (bid >= 1600) {   // histogram part
        int b2 = bid - 1600;
        if (t < E_TYPES) lh[t] = 0;
        __syncthreads();
        int idx = b2 * 256 + t;
        if (idx < N_TOK) atomicAdd(&lh[aatype[idx]], 1);
        __syncthreads();
        if (t < E_TYPES) wsI[HIST_OFF + b2 * E_TYPES + t] = lh[t];
        return;
    }
    int gid = bid * 256 + t;
    unsigned short h[8], l[8];
    if (gid < 245760) {          // phase-1 weights: 20*8*24 blocks x 64 lanes
        int lane = gid & 63;
        int bi = gid >> 6;
        int kb = bi % 24;
        int r = bi / 24;
        int nt = r & 7, e = r >> 3;
        int n = nt * 16 + (lane & 15);
        int k0 = kb * 32 + (lane >> 4) * 8;
        #pragma unroll
        for (int j = 0; j < 8; j++) {
            int k = k0 + j;
            float x = (k < CS) ? Win[((size_t)e * CS + k) * CH + n]
                               : Winit[((size_t)e * CS + (k - CS)) * CH + n];
            split_bf16(x, h[j], l[j]);
        }
        unsigned short* dst = wt + (WT1_OFF / 2) + (size_t)bi * 1024 + lane * 8;
        *(bfrag*)dst = *(bfrag*)h;
        *(bfrag*)(dst + 512) = *(bfrag*)l;
    } else {                     // residual weights: 20*4*8*4 blocks x 64 lanes
        gid -= 245760;
        int lane = gid & 63;
        int bi = gid >> 6;       // 0..2559
        int kb = bi & 3;
        int nt = (bi >> 2) & 7;
        int m4 = (bi >> 5) & 3;
        int e = bi >> 7;
        int b = m4 >> 1;
        const float* W = (m4 & 1) ? Wb2 : Wb1;
        int n = nt * 16 + (lane & 15);
        int k0 = kb * 32 + (lane >> 4) * 8;
        #pragma unroll
        for (int j = 0; j < 8; j++) {
            int k = k0 + j;
            float x = W[(((size_t)e * NBLK + b) * CH + k) * CH + n];
            split_bf16(x, h[j], l[j]);
        }
        unsigned short* dst = wt + (WTR_OFF / 2) + (size_t)bi * 1024 + lane * 8;
        *(bfrag*)dst = *(bfrag*)h;
        *(bfrag*)(dst + 512) = *(bfrag*)l;
    }
}

#define MFMA(a, b, c) __builtin_amdgcn_mfma_f32_16x16x32_bf16((a), (b), (c), 0, 0, 0)

// MFMAs for one k-slice: MF m-frags x 2 n-frags x (hi/lo triple).
// Per-acc-chain order identical to prior rounds (bitwise-same result).
#define KS_MFMA(MF, MROW, WAH, WAL, KS, BHA, BLA, BHB, BLB) do {       \
    int kl = (KS) * 32 + quad * 8;                                     \
    _Pragma("unroll")                                                  \
    for (int m = 0; m < (MF); m++) {                                   \
        bfrag ah = *(const bfrag*)&WAH[(MROW) + m * 16 + lane15][kl];  \
        bfrag al = *(const bfrag*)&WAL[(MROW) + m * 16 + lane15][kl];  \
        gA0[m] = MFMA(ah, BHA, gA0[m]);                                \
        gB0[m] = MFMA(ah, BLA, gB0[m]);                                \
        gB0[m] = MFMA(al, BHA, gB0[m]);                                \
        gA1[m] = MFMA(ah, BHB, gA1[m]);                                \
        gB1[m] = MFMA(ah, BLB, gB1[m]);                                \
        gB1[m] = MFMA(al, BHB, gB1[m]);                                \
    }                                                                  \
} while (0)

// One K=128 stage, k-slice weight pipeline (r9-proven, no spill):
// Wp0..3 hold ks0 for both n-frags (prefetched across the barrier);
// ks1-3's 12 fragments are transient at entry; Wp reloads for the NEXT
// stage right after ks0's MFMAs. Peak live weight regs ~64 VGPR.
#define MFMA_STAGE(MF, MROW, WAH, WAL, PA, PB, NPA, NPB) do {          \
    bfrag w1a = (PA)[128], w1l = (PA)[192], w1b = (PB)[128], w1m = (PB)[192]; \
    bfrag w2a = (PA)[256], w2l = (PA)[320], w2b = (PB)[256], w2m = (PB)[320]; \
    bfrag w3a = (PA)[384], w3l = (PA)[448], w3b = (PB)[384], w3m = (PB)[448]; \
    KS_MFMA(MF, MROW, WAH, WAL, 0, Wp0, Wp1, Wp2, Wp3);                \
    Wp0 = (NPA)[0]; Wp1 = (NPA)[64]; Wp2 = (NPB)[0]; Wp3 = (NPB)[64];  \
    KS_MFMA(MF, MROW, WAH, WAL, 1, w1a, w1l, w1b, w1m);                \
    KS_MFMA(MF, MROW, WAH, WAL, 2, w2a, w2l, w2b, w2m);                \
    KS_MFMA(MF, MROW, WAH, WAL, 3, w3a, w3l, w3b, w3m);                \
} while (0)

// Write relu of this wave's tile (MF m-frags from MROW x 2 n-frags,
// C layout) as split-bf16 A for the next GEMM. Tiles are disjoint.
#define WRITE_H2(MF, MROW, WAH, WAL, S0, S1) do {                  \
    _Pragma("unroll")                                              \
    for (int m = 0; m < (MF); m++)                                 \
    {                                                              \
        _Pragma("unroll")                                          \
        for (int rr = 0; rr < 4; rr++) {                           \
            int row = (MROW) + m * 16 + quad * 4 + rr;             \
            unsigned short hh, ll;                                 \
            split_bf16(fmaxf(S0[m][rr], 0.f), hh, ll);             \
            WAH[row][nc0] = hh;                                    \
            WAL[row][nc0] = ll;                                    \
            split_bf16(fmaxf(S1[m][rr], 0.f), hh, ll);             \
            WAH[row][nc1] = hh;                                    \
            WAL[row][nc1] = ll;                                    \
        }                                                          \
    }                                                              \
} while (0)

// Stage one 16-float activation segment (relu + split) into LDS.
__device__ __forceinline__ void stage_seg(arr136 WAH, arr136 WAL, int row, int col,
                                          float4 a, float4 b, float4 c, float4 d) {
    float xv[16] = {a.x, a.y, a.z, a.w, b.x, b.y, b.z, b.w,
                    c.x, c.y, c.z, c.w, d.x, d.y, d.z, d.w};
    unsigned short h8[8], l8[8];
    #pragma unroll
    for (int j = 0; j < 8; j++) split_bf16(fmaxf(xv[j], 0.f), h8[j], l8[j]);
    *(bfrag*)&WAH[row][col] = *(bfrag*)h8;
    *(bfrag*)&WAL[row][col] = *(bfrag*)l8;
    #pragma unroll
    for (int j = 0; j < 8; j++) split_bf16(fmaxf(xv[8 + j], 0.f), h8[j], l8[j]);
    *(bfrag*)&WAH[row][col + 8] = *(bfrag*)h8;
    *(bfrag*)&WAL[row][col + 8] = *(bfrag*)l8;
}

// TOK=80, 512 thr, 8 waves = 2 m-groups x 4 n-groups. Wave tile:
// mw0 = 48x32 (3 m-frags), mw1 = 32x32 (2 m-frags); 2 n-frags each, so
// every A-fragment read feeds 2 n-frags (half the LDS read traffic of
// the 5x1 mapping) at the SAME full-fill grid (224 <= 256).
__global__ __launch_bounds__(TPB_MAIN, 2)
void angle_main(const float* __restrict__ s, const float* __restrict__ si,
                const float* __restrict__ b_in, const float* __restrict__ b_init2,
                const float* __restrict__ bb1, const float* __restrict__ bb2,
                const float* __restrict__ Wout, const float* __restrict__ b_out,
                const int* __restrict__ aatype,
                const int* __restrict__ wsI, const unsigned short* __restrict__ wt,
                float* __restrict__ out)
{
    // LDS pool: two (Ah,Al) buffers of [80][136] u16; epilogue Hf/Of overlap.
    #define ABUF 21760
    __shared__ __align__(16) char pool[4 * ABUF];
    __shared__ int ptok[TOK];
    __shared__ int cntS[E_TYPES];

    arr136 AH0 = (arr136)(pool);
    arr136 AL0 = (arr136)(pool + ABUF);
    arr136 AH1 = (arr136)(pool + 2 * ABUF);
    arr136 AL1 = (arr136)(pool + 3 * ABUF);
    float (*Hf)[132] = (float (*)[132])(pool);            // 80*132*4 = 42240 <= 2*ABUF
    float (*Of)[16]  = (float (*)[16])(pool + 2 * ABUF);  // 5KB

    int t = threadIdx.x;
    int w = t >> 6, lane = t & 63;
    int lane15 = lane & 15, quad = lane >> 4;
    int mw = w >> 2, nw = w & 3;              // wave tile coords
    int nc0 = nw * 32 + lane15;
    int nc1 = nc0 + 16;
    int nt0 = nw * 2, nt1 = nw * 2 + 1;       // weight n-tile indices

    // XCD-chunked bijective swizzle (e-sorted tiles -> per-XCD L2 residency).
    int bid = blockIdx.x;
    const int q = MAX_TILES >> 3, r = MAX_TILES & 7;   // 28, 0
    int xcd = bid & 7, sub = bid >> 3;
    int tile = (xcd < r ? xcd * (q + 1) : r * (q + 1) + (xcd - r) * q) + sub;

    // wave0: per-type totals from the 64x20 chunk histograms
    if (w == 0 && lane < E_TYPES) {
        int c = 0;
        #pragma unroll
        for (int b = 0; b < NPREP; b++) c += wsI[HIST_OFF + b * E_TYPES + lane];
        cntS[lane] = c;
    }
    __syncthreads();

    int pos = tile * TOK;
    int e = -1, poff_e = 0;
    {
        int accT = 0;
        #pragma unroll
        for (int ee = 0; ee < E_TYPES; ee++) {
            int pad = ((cntS[ee] + TOK - 1) / TOK) * TOK;   // TOK not pow2
            if (e < 0 && pos < accT + pad) { e = ee; poff_e = accT; }
            accT += pad;
        }
        if (pos >= accT) return;     // uniform exit (all waves agree)
    }
    int pos_in = pos - poff_e;
    int n = cntS[e] - pos_in; if (n > TOK) n = TOK;

    const bfrag* wt1 = (const bfrag*)((const char*)wt + WT1_OFF);
    const bfrag* wtr = (const bfrag*)((const char*)wt + WTR_OFF);
    size_t wb0 = (size_t)(e * 8 + nt0) * 24;
    size_t wb1 = (size_t)(e * 8 + nt1) * 24;

    // Early issue: stage-0 ks0 weights (both n-frags) + all bias values.
    bfrag Wp0, Wp1, Wp2, Wp3;
    {
        const bfrag* pa0 = wt1 + wb0 * 128 + lane;
        const bfrag* pb0 = wt1 + wb1 * 128 + lane;
        Wp0 = pa0[0]; Wp1 = pa0[64]; Wp2 = pb0[0]; Wp3 = pb0[64];
    }
    float bv_in0 = b_in[e * CH + nc0] + b_init2[e * CH + nc0];
    float bv_in1 = b_in[e * CH + nc1] + b_init2[e * CH + nc1];
    float bvb1a0 = bb1[(e * NBLK + 0) * CH + nc0], bvb1a1 = bb1[(e * NBLK + 0) * CH + nc1];
    float bvb1b0 = bb1[(e * NBLK + 1) * CH + nc0], bvb1b1 = bb1[(e * NBLK + 1) * CH + nc1];
    float bvb2a0 = bb2[(e * NBLK + 0) * CH + nc0], bvb2a1 = bb2[(e * NBLK + 0) * CH + nc1];
    float bvb2b0 = bb2[(e * NBLK + 1) * CH + nc0], bvb2b1 = bb2[(e * NBLK + 1) * CH + nc1];

    // wave0: rank-scan aatype -> ptok (tokens with rank [pos_in, pos_in+n))
    if (w == 0) {
        int hb = wsI[HIST_OFF + lane * E_TYPES + e];
        int inc = hb;
        #pragma unroll
        for (int d = 1; d < 64; d <<= 1) { int v = __shfl_up(inc, d); if (lane >= d) inc += v; }
        int pre = inc - hb;
        unsigned long long mle = __ballot(pre <= pos_in);
        int cb = 63 - __clzll(mle);
        int running = __shfl(pre, cb);
        int base = cb * 256;
        int lim = pos_in + n;
        while (running < lim && base < N_TOK) {
            const int4 a4 = *(const int4*)&aatype[base + lane * 4];
            int m0 = (a4.x == e), m1 = (a4.y == e), m2 = (a4.z == e), m3 = (a4.w == e);
            int c = m0 + m1 + m2 + m3;
            int incl = c;
            #pragma unroll
            for (int d = 1; d < 64; d <<= 1) { int v = __shfl_up(incl, d); if (lane >= d) incl += v; }
            int rk = running + incl - c;
            int tk = base + lane * 4;
            if (m0) { if (rk >= pos_in && rk < lim) ptok[rk - pos_in] = tk;     rk++; }
            if (m1) { if (rk >= pos_in && rk < lim) ptok[rk - pos_in] = tk + 1; rk++; }
            if (m2) { if (rk >= pos_in && rk < lim) ptok[rk - pos_in] = tk + 2; rk++; }
            if (m3) { if (rk >= pos_in && rk < lim) ptok[rk - pos_in] = tk + 3; rk++; }
            running += __shfl(incl, 63);
            base += 256;
        }
        int t0v = ptok[0];
        for (int i = n + lane; i < TOK; i += 64) ptok[i] = t0v;   // pad w/ dup token
    }
    __syncthreads();

    // ---- phase 1: h = [relu(s) relu(si)] @ [Win;Winit] + biases, K=768 ----
    // Staging: 640 segs (80 rows x 8) over 512 threads; waves 0-1 take a
    // second seg (wave-uniform). One chunk prefetched ahead in regs.
    int srow0 = t >> 3;
    int scol0 = (t & 7) * 16;
    bool has2 = (t < TOK * 8 - TPB_MAIN);    // t < 128
    int srow1 = srow0 + 64;
    size_t ro0 = (size_t)ptok[srow0] * CS + scol0;
    size_t ro1 = has2 ? ((size_t)ptok[srow1] * CS + scol0) : ro0;
    float4 p0 = *(const float4*)(s + ro0);
    float4 p1 = *(const float4*)(s + ro0 + 4);
    float4 p2 = *(const float4*)(s + ro0 + 8);
    float4 p3 = *(const float4*)(s + ro0 + 12);
    float4 q0, q1, q2, q3;
    if (has2) {
        q0 = *(const float4*)(s + ro1);
        q1 = *(const float4*)(s + ro1 + 4);
        q2 = *(const float4*)(s + ro1 + 8);
        q3 = *(const float4*)(s + ro1 + 12);
    }

    f32x4 gA0[3], gB0[3], gA1[3], gB1[3];
    #pragma unroll
    for (int m = 0; m < 3; m++) {
        gA0[m] = (f32x4){bv_in0, bv_in0, bv_in0, bv_in0};
        gA1[m] = (f32x4){bv_in1, bv_in1, bv_in1, bv_in1};
        gB0[m] = (f32x4){0.f, 0.f, 0.f, 0.f};
        gB1[m] = gB0[m];
    }

    #pragma unroll
    for (int c = 0; c < 6; c++) {
        arr136 WAH = (c & 1) ? AH1 : AH0;
        arr136 WAL = (c & 1) ? AL1 : AL0;
        stage_seg(WAH, WAL, srow0, scol0, p0, p1, p2, p3);
        if (has2) stage_seg(WAH, WAL, srow1, scol0, q0, q1, q2, q3);
        if (c < 5) {   // prefetch next chunk activations
            const float* src = (c + 1 < 3) ? s : si;
            int kb0 = ((c + 1 < 3) ? (c + 1) : (c - 2)) * KC;
            p0 = *(const float4*)(src + ro0 + kb0);
            p1 = *(const float4*)(src + ro0 + kb0 + 4);
            p2 = *(const float4*)(src + ro0 + kb0 + 8);
            p3 = *(const float4*)(src + ro0 + kb0 + 12);
            if (has2) {
                q0 = *(const float4*)(src + ro1 + kb0);
                q1 = *(const float4*)(src + ro1 + kb0 + 4);
                q2 = *(const float4*)(src + ro1 + kb0 + 8);
                q3 = *(const float4*)(src + ro1 + kb0 + 12);
            }
        }
        __syncthreads();
        const bfrag* pa = wt1 + (wb0 + c * 4) * 128 + lane;
        const bfrag* pb = wt1 + (wb1 + c * 4) * 128 + lane;
        const bfrag* npa = (c < 5) ? wt1 + (wb0 + (c + 1) * 4) * 128 + lane
                                   : wtr + (((size_t)(e * 4) * 8 + nt0) * 4) * 128 + lane;
        const bfrag* npb = (c < 5) ? wt1 + (wb1 + (c + 1) * 4) * 128 + lane
                                   : wtr + (((size_t)(e * 4) * 8 + nt1) * 4) * 128 + lane;
        if ((c & 1) == 0) {
            if (mw == 0) MFMA_STAGE(3, 0,  AH0, AL0, pa, pb, npa, npb);
            else         MFMA_STAGE(2, 48, AH0, AL0, pa, pb, npa, npb);
        } else {
            if (mw == 0) MFMA_STAGE(3, 0,  AH1, AL1, pa, pb, npa, npb);
            else         MFMA_STAGE(2, 48, AH1, AL1, pa, pb, npa, npb);
        }
    }

    // ---- residual blocks: 4 GEMMs, one barrier each ----
    f32x4 h0[3], h1[3];
    #pragma unroll
    for (int m = 0; m < 3; m++) { h0[m] = gA0[m] + gB0[m]; h1[m] = gA1[m] + gB1[m]; }
    if (mw == 0) WRITE_H2(3, 0,  AH0, AL0, h0, h1);
    else         WRITE_H2(2, 48, AH0, AL0, h0, h1);
    __syncthreads();

    #pragma unroll
    for (int g = 0; g < 4; g++) {
        float bv0 = (g == 0) ? bvb1a0 : (g == 1) ? bvb2a0 : (g == 2) ? bvb1b0 : bvb2b0;
        float bv1 = (g == 0) ? bvb1a1 : (g == 1) ? bvb2a1 : (g == 2) ? bvb1b1 : bvb2b1;
        #pragma unroll
        for (int m = 0; m < 3; m++) {
            gA0[m] = (f32x4){bv0, bv0, bv0, bv0};
            gA1[m] = (f32x4){bv1, bv1, bv1, bv1};
            gB0[m] = (f32x4){0.f, 0.f, 0.f, 0.f};
            gB1[m] = gB0[m];
        }
        arr136 WAH = (g & 1) ? AH1 : AH0;
        arr136 WAL = (g & 1) ? AL1 : AL0;
        const bfrag* pa  = wtr + (((size_t)(e * 4 + g) * 8 + nt0) * 4) * 128 + lane;
        const bfrag* pb  = wtr + (((size_t)(e * 4 + g) * 8 + nt1) * 4) * 128 + lane;
        const bfrag* npa = (g < 3) ? wtr + (((size_t)(e * 4 + g + 1) * 8 + nt0) * 4) * 128 + lane
                                   : pa;   // dummy next (unused)
        const bfrag* npb = (g < 3) ? wtr + (((size_t)(e * 4 + g + 1) * 8 + nt1) * 4) * 128 + lane
                                   : pb;
        if (mw == 0) MFMA_STAGE(3, 0,  WAH, WAL, pa, pb, npa, npb);
        else         MFMA_STAGE(2, 48, WAH, WAL, pa, pb, npa, npb);
        if (g & 1) {   // end of a residual block: h += W2 out
            #pragma unroll
            for (int m = 0; m < 3; m++) { h0[m] += gA0[m] + gB0[m]; h1[m] += gA1[m] + gB1[m]; }
            if (g < 3) {
                if (mw == 0) WRITE_H2(3, 0,  AH0, AL0, h0, h1);
                else         WRITE_H2(2, 48, AH0, AL0, h0, h1);
                __syncthreads();
            }
        } else {       // mid-block: a1 = relu-input for W2
            #pragma unroll
            for (int m = 0; m < 3; m++) { gA0[m] += gB0[m]; gA1[m] += gB1[m]; }
            if (mw == 0) WRITE_H2(3, 0,  AH1, AL1, gA0, gA1);
            else         WRITE_H2(2, 48, AH1, AL1, gA0, gA1);
            __syncthreads();
        }
    }

    // ---- epilogue: relu(h) fp32 -> Hf (buf0 region; g3 readers used buf1) ----
    if (mw == 0) {
        #pragma unroll
        for (int m = 0; m < 3; m++)
            #pragma unroll
            for (int rr = 0; rr < 4; rr++) {
                int row = m * 16 + quad * 4 + rr;
                Hf[row][nc0] = fmaxf(h0[m][rr], 0.f);
                Hf[row][nc1] = fmaxf(h1[m][rr], 0.f);
            }
    } else {
        #pragma unroll
        for (int m = 0; m < 2; m++)
            #pragma unroll
            for (int rr = 0; rr < 4; rr++) {
                int row = 48 + m * 16 + quad * 4 + rr;
                Hf[row][nc0] = fmaxf(h0[m][rr], 0.f);
                Hf[row][nc1] = fmaxf(h1[m][rr], 0.f);
            }
    }
    __syncthreads();

    // ---- out = relu(h) @ Wout + b_out (128 -> 14), 4-way partials ----
    const float* WoutE = Wout + (size_t)e * CH * (NANG * 2);
    const float* boutE = b_out + (size_t)e * (NANG * 2);
    for (int idx = t; idx < n * (NANG * 2); idx += TPB_MAIN) {
        int i = idx / (NANG * 2);
        int o = idx - i * (NANG * 2);
        float v0 = boutE[o], v1 = 0.f, v2 = 0.f, v3 = 0.f;
        #pragma unroll 4
        for (int k = 0; k < CH; k += 4) {
            v0 = fmaf(Hf[i][k],     WoutE[(size_t)k * (NANG * 2) + o],       v0);
            v1 = fmaf(Hf[i][k + 1], WoutE[(size_t)(k + 1) * (NANG * 2) + o], v1);
            v2 = fmaf(Hf[i][k + 2], WoutE[(size_t)(k + 2) * (NANG * 2) + o], v2);
            v3 = fmaf(Hf[i][k + 3], WoutE[(size_t)(k + 3) * (NANG * 2) + o], v3);
        }
        Of[i][o] = (v0 + v1) + (v2 + v3);
    }
    __syncthreads();

    // ---- pair-normalize and store ----
    for (int idx = t; idx < n * NANG; idx += TPB_MAIN) {
        int i = idx / NANG;
        int a = idx - i * NANG;
        float x = Of[i][2 * a];
        float y = Of[i][2 * a + 1];
        float nr = fmaxf(sqrtf(x * x + y * y), 1e-12f);
        size_t base = (size_t)ptok[i] * (NANG * 2) + 2 * a;
        out[base]     = x / nr;
        out[base + 1] = y / nr;
    }
}

extern "C" void kernel_launch(void* const* d_in, const int* in_sizes, int n_in,
                              void* d_out, int out_size, void* d_ws, size_t ws_size,
                              hipStream_t stream) {
    const float* s       = (const float*)d_in[0];
    const float* s_init  = (const float*)d_in[1];
    const int*   aatype  = (const int*)d_in[2];
    const float* Win     = (const float*)d_in[3];
    const float* b_in    = (const float*)d_in[4];
    const float* Winit   = (const float*)d_in[5];
    const float* b_init2 = (const float*)d_in[6];
    const float* Wb1     = (const float*)d_in[7];
    const float* bb1     = (const float*)d_in[8];
    const float* Wb2     = (const float*)d_in[9];
    const float* bb2     = (const float*)d_in[10];
    const float* Wout    = (const float*)d_in[11];
    const float* b_out   = (const float*)d_in[12];
    int* wsI = (int*)d_ws;
    unsigned short* wt = (unsigned short*)d_ws;
    float* out = (float*)d_out;

    hipLaunchKernelGGL(prep1, dim3(1664), dim3(256), 0, stream,
                       Win, Winit, Wb1, Wb2, aatype, wsI, wt);
    hipLaunchKernelGGL(angle_main, dim3(MAX_TILES), dim3(TPB_MAIN), 0, stream,
                       s, s_init, b_in, b_init2, bb1, bb2, Wout, b_out,
                       aatype, wsI, wt, out);
}